// Round 9
// baseline (229.395 us; speedup 1.0000x reference)
//
#include <hip/hip_runtime.h>
#include <hip/hip_bf16.h>

// Problem constants
#define DM   1024
#define NH   16
#define DK   64
#define RK   16
#define BB   2
#define LL   2048
#define TT   (BB*LL)
#define NSPL 2             // split-K factor

// r18: r17 4-dispatch timeline + T3/T4 "minimum 2-phase" pipeline (m248
// recipe) in proj & outred: LDS double-buffer, raw s_barrier, ONE vmcnt(0)
// per iter AFTER the MFMAs -> next-tile global_load_lds stays in flight
// across the ds_read+MFMA phase instead of draining every iteration.
// outred: P0/P1 DMA-staged; reduce math moved to frag-read with pre-built
// vsS/invS LDS tables (loop contains only DMA VMEM -> clean vmcnt).
// prep_k and attn_k unchanged from r17.

typedef float f4   __attribute__((ext_vector_type(4)));
typedef float f16v __attribute__((ext_vector_type(16)));
typedef short s8v  __attribute__((ext_vector_type(8)));
typedef unsigned int u2v __attribute__((ext_vector_type(2)));
typedef unsigned int u4v __attribute__((ext_vector_type(4)));

static __device__ __forceinline__ unsigned short f2b(float f) {
  __hip_bfloat16 h = __float2bfloat16(f);
  unsigned short u;
  __builtin_memcpy(&u, &h, 2);
  return u;
}
static __device__ __forceinline__ float b2f(unsigned short u) {
  __hip_bfloat16 h;
  __builtin_memcpy(&h, &u, 2);
  return __bfloat162float(h);
}

// async global->LDS, 16 B per lane. LDS dest wave-uniform base + lane*16.
static __device__ __forceinline__ void gld_lds16(const void* g, void* l) {
  __builtin_amdgcn_global_load_lds(
      (const __attribute__((address_space(1))) unsigned int*)g,
      (__attribute__((address_space(3))) unsigned int*)l, 16, 0, 0);
}

static __device__ __forceinline__ void wait_vm0_barrier() {
  asm volatile("s_waitcnt vmcnt(0)" ::: "memory");
  __builtin_amdgcn_s_barrier();
}

// ---------------------------------------------------------------------------
// prep: blockIdx.x ranges
//   [0,1024)    cast x_q   [1024,2048) cast x_kv
//   [2048,2304) cast Wv    [2304,2560) cast Wo
//   [2560,3072) fuse_w     [3072] bias2
// ---------------------------------------------------------------------------
static __device__ __forceinline__ void cast_rng(
    const float* __restrict__ s, unsigned short* __restrict__ d,
    int n4, int lb, int nb, int tid) {
  for (int i = lb*256 + tid; i < n4; i += nb*256) {
    const float4 v = ((const float4*)s)[i];
    ushort4 o;
    o.x = f2b(v.x); o.y = f2b(v.y); o.z = f2b(v.z); o.w = f2b(v.w);
    ((ushort4*)d)[i] = o;
  }
}

__global__ __launch_bounds__(256) void prep_k(
    const float* __restrict__ xq,  const float* __restrict__ xkv,
    const float* __restrict__ Wv,  const float* __restrict__ Wo,
    unsigned short* __restrict__ xq_b,  unsigned short* __restrict__ xkv_b,
    unsigned short* __restrict__ Wv_b,  unsigned short* __restrict__ Wo_b,
    const float* __restrict__ Wq,  const float* __restrict__ Wk,
    const float* __restrict__ Uq,  const float* __restrict__ Uk,
    unsigned short* __restrict__ Aq, unsigned short* __restrict__ Ak,
    const float* __restrict__ bq,  const float* __restrict__ bk,
    float* __restrict__ bpq, float* __restrict__ bpk) {
  __shared__ float sh[64*16 + 4*64];
  const int x = blockIdx.x, tid = threadIdx.x;
  if (x < 1024) {
    cast_rng(xq,  xq_b,  TT*DM/4, x,        1024, tid);
  } else if (x < 2048) {
    cast_rng(xkv, xkv_b, TT*DM/4, x - 1024, 1024, tid);
  } else if (x < 2304) {
    cast_rng(Wv,  Wv_b,  DM*DM/4, x - 2048, 256, tid);
  } else if (x < 2560) {
    cast_rng(Wo,  Wo_b,  DM*DM/4, x - 2304, 256, tid);
  } else if (x < 3072) {
    const int fidx = x - 2560;
    const int sel = fidx >> 8, f = fidx & 255;
    const float* W = sel ? Wk : Wq;
    const float* U = sel ? Uk : Uq;
    unsigned short* At = sel ? Ak : Aq;
    const int i0 = (f & 15) * 64, h = f >> 4;
    float* Us = sh;            // [64][16]
    float* Ws = sh + 1024;     // [4][64]
    const int il = tid & 63, rr = tid >> 6;
    for (int t = tid; t < 64*16; t += 256)
      Us[t] = U[(size_t)(h*DK + (t >> 4))*RK + (t & 15)];
    float acc[4] = {};
    for (int d0 = 0; d0 < DK; d0 += 4) {
      __syncthreads();
      Ws[rr*64 + il] = W[(size_t)(h*DK + d0 + rr)*DM + i0 + il];
      __syncthreads();
#pragma unroll
      for (int dd = 0; dd < 4; ++dd) {
        const float w = Ws[dd*64 + il];
#pragma unroll
        for (int j = 0; j < 4; ++j)
          acc[j] += w * Us[(d0 + dd)*16 + rr*4 + j];
      }
    }
#pragma unroll
    for (int j = 0; j < 4; ++j)
      At[(size_t)(h*RK + rr*4 + j)*DM + i0 + il] = f2b(acc[j]);
  } else {
    const int h = tid >> 4, r = tid & 15;
    float aq = 0.f, ak = 0.f;
    for (int d = 0; d < DK; ++d) {
      aq += bq[h*DK + d] * Uq[(size_t)(h*DK + d)*RK + r];
      ak += bk[h*DK + d] * Uk[(size_t)(h*DK + d)*RK + r];
    }
    bpq[tid] = aq; bpk[tid] = ak;
  }
}

// ---------------------------------------------------------------------------
// proj: f<256 -> QpKp 64x128 GEMM; f>=256 -> Vt 128x128 GEMM.
// Both: 2-phase dbuf pipeline (stage t+1 first, vmcnt(0)+barrier AFTER MFMA).
// ---------------------------------------------------------------------------
__global__ __launch_bounds__(256) void proj_k(
    const unsigned short* __restrict__ xq_b, const unsigned short* __restrict__ xkv_b,
    const unsigned short* __restrict__ Atq,  const unsigned short* __restrict__ Atk,
    const float* __restrict__ bpq, const float* __restrict__ bpk,
    unsigned short* __restrict__ Qp, unsigned short* __restrict__ Kp,
    const unsigned short* __restrict__ Wv_b, const float* __restrict__ bv,
    unsigned short* __restrict__ Vt) {
  __shared__ __align__(16) unsigned short shm[16384];   // 32 KB
  const int f = blockIdx.x, tid = threadIdx.x;
  const int wave = tid >> 6, lane = tid & 63;
  const int quad = lane >> 4, l15 = lane & 15;
  const int ar = tid >> 2, ac = (tid & 3) * 8;
  const f4 z = {0.f, 0.f, 0.f, 0.f};

  if (f < 256) {
    // ---- QpKp: 64x128 tile, N=256 ----
    const int xb = f & 63, yb = (f >> 6) & 1, zb = f >> 7;
    const unsigned short* Ag = zb ? xkv_b : xq_b;
    const unsigned short* Bg = zb ? Atk : Atq;
    const float* bias = zb ? bpk : bpq;
    unsigned short* C = zb ? Kp : Qp;
    unsigned short* Xs = shm;          // [2][2048]
    unsigned short* Bq = shm + 4096;   // [2][4096]
    const int t0 = xb*64, n0 = yb*128, nh = wave*32;
    f4 acc[4][2];
#pragma unroll
    for (int a = 0; a < 4; ++a) { acc[a][0] = z; acc[a][1] = z; }

    auto STAGE = [&](int buf, int k0) {
      gld_lds16(&Ag[(size_t)(t0 + ar)*DM + k0 + ac],      &Xs[buf*2048 + wave*512]);
      gld_lds16(&Bg[(size_t)(n0 + ar)*DM + k0 + ac],      &Bq[buf*4096 + wave*512]);
      gld_lds16(&Bg[(size_t)(n0 + 64 + ar)*DM + k0 + ac], &Bq[buf*4096 + 2048 + wave*512]);
    };
    STAGE(0, 0);
    wait_vm0_barrier();
    int cur = 0;
    for (int k0 = 0; k0 < DM; k0 += 32) {
      if (k0 + 32 < DM) STAGE(cur ^ 1, k0 + 32);
      s8v af[4], bf[2];
#pragma unroll
      for (int ms = 0; ms < 4; ++ms)
        af[ms] = *(const s8v*)&Xs[cur*2048 + (ms*16 + l15)*32 + quad*8];
#pragma unroll
      for (int ns = 0; ns < 2; ++ns)
        bf[ns] = *(const s8v*)&Bq[cur*4096 + (nh + ns*16 + l15)*32 + quad*8];
#pragma unroll
      for (int ms = 0; ms < 4; ++ms)
#pragma unroll
        for (int ns = 0; ns < 2; ++ns)
          acc[ms][ns] = __builtin_amdgcn_mfma_f32_16x16x32_bf16(
              af[ms], bf[ns], acc[ms][ns], 0, 0, 0);
      wait_vm0_barrier();
      cur ^= 1;
    }
#pragma unroll
    for (int ms = 0; ms < 4; ++ms) {
      const int tb = t0 + ms*16 + quad*4;
#pragma unroll
      for (int ns = 0; ns < 2; ++ns) {
        const int o = n0 + nh + ns*16 + l15;
        const float bvv = bias[o];
        f4 a = acc[ms][ns];
#pragma unroll
        for (int rg = 0; rg < 4; ++rg) {
          const int tt = tb + rg;   // packed [b][h][l][16]
          C[(((size_t)(tt >> 11)*NH + (o >> 4))*LL + (tt & 2047))*RK + (o & 15)]
              = f2b(a[rg] + bvv);
        }
      }
    }
  } else {
    // ---- Vt: 128x128 tile ----
    const int g = f - 256, gx = g & 31, gy = g >> 5;
    unsigned short* As = shm;          // [2][4096]
    unsigned short* Bs = shm + 8192;   // [2][4096]
    const int t0 = gx*128, n0 = gy*128;
    f4 acc[2][8];
#pragma unroll
    for (int m = 0; m < 2; ++m)
#pragma unroll
      for (int n = 0; n < 8; ++n) acc[m][n] = z;

    auto STAGE = [&](int buf, int k0) {
      gld_lds16(&xkv_b[(size_t)(t0 + ar)*DM + k0 + ac],      &As[buf*4096 + wave*512]);
      gld_lds16(&xkv_b[(size_t)(t0 + 64 + ar)*DM + k0 + ac], &As[buf*4096 + 2048 + wave*512]);
      gld_lds16(&Wv_b[(size_t)(n0 + ar)*DM + k0 + ac],       &Bs[buf*4096 + wave*512]);
      gld_lds16(&Wv_b[(size_t)(n0 + 64 + ar)*DM + k0 + ac],  &Bs[buf*4096 + 2048 + wave*512]);
    };
    STAGE(0, 0);
    wait_vm0_barrier();
    int cur = 0;
    for (int k0 = 0; k0 < DM; k0 += 32) {
      if (k0 + 32 < DM) STAGE(cur ^ 1, k0 + 32);
      s8v af[2], bf[8];
#pragma unroll
      for (int ms = 0; ms < 2; ++ms)
        af[ms] = *(const s8v*)&As[cur*4096 + (wave*32 + ms*16 + l15)*32 + quad*8];
#pragma unroll
      for (int ns = 0; ns < 8; ++ns)
        bf[ns] = *(const s8v*)&Bs[cur*4096 + (ns*16 + l15)*32 + quad*8];
#pragma unroll
      for (int ms = 0; ms < 2; ++ms)
#pragma unroll
        for (int ns = 0; ns < 8; ++ns)
          acc[ms][ns] = __builtin_amdgcn_mfma_f32_16x16x32_bf16(
              af[ms], bf[ns], acc[ms][ns], 0, 0, 0);
      wait_vm0_barrier();
      cur ^= 1;
    }
#pragma unroll
    for (int ms = 0; ms < 2; ++ms) {
      const int tb = t0 + wave*32 + ms*16 + quad*4;
#pragma unroll
      for (int ns = 0; ns < 8; ++ns) {
        const int o = n0 + ns*16 + l15;
        const float bvv = bv[o];
        f4 a = acc[ms][ns];
        const int bb = tb >> 11, l = tb & 2047;   // Vt[b][o][l]
        ushort4 pk;
        pk.x = f2b(a[0] + bvv); pk.y = f2b(a[1] + bvv);
        pk.z = f2b(a[2] + bvv); pk.w = f2b(a[3] + bvv);
        *(ushort4*)&Vt[((size_t)bb*DM + o)*LL + l] = pk;
      }
    }
  }
}

// ---------------------------------------------------------------------------
// softmax + bf16-pack for one 64k x 32q S^T pair (unchanged from r17).
// ---------------------------------------------------------------------------
template<bool MASKED>
static __device__ __forceinline__ void softmax_pack(
    const f16v& s0, const f16v& s1, const unsigned long long mb, const int hi,
    float& den, unsigned int (&Pd)[2][4][2]) {
#pragma unroll
  for (int nt = 0; nt < 2; ++nt) {
    const f16v& sv = nt ? s1 : s0;
#pragma unroll
    for (int r = 0; r < 4; ++r) {
      float ep[4];
#pragma unroll
      for (int j = 0; j < 4; ++j) {
        float em = __expf(sv[r*4 + j] * 0.25f);
        if (MASKED) {
          const int kloc = nt*32 + j + 8*r + 4*hi;
          if ((mb >> kloc) & 1ull) em = 0.f;
        }
        den += em;
        ep[j] = em - 1.f;
      }
      asm("v_cvt_pk_bf16_f32 %0, %1, %2"
          : "=v"(Pd[nt][r][0]) : "v"(ep[0]), "v"(ep[1]));
      asm("v_cvt_pk_bf16_f32 %0, %1, %2"
          : "=v"(Pd[nt][r][1]) : "v"(ep[2]), "v"(ep[3]));
    }
  }
}

// ---------------------------------------------------------------------------
// attn: z<4 -> attention (split-K + permlane32_swap); z==4, y<BB -> vsum.
// P layout: [split][t][dm] bf16. Unchanged from r17.
// ---------------------------------------------------------------------------
__global__ __launch_bounds__(256) void attn_k(
    const unsigned short* __restrict__ Qp, const unsigned short* __restrict__ Kp,
    const unsigned short* __restrict__ Vt,
    const unsigned char* __restrict__ msk,
    unsigned short* __restrict__ P, float* __restrict__ denP,
    float* __restrict__ Vsum) {
  __shared__ __align__(16) unsigned short Ks[2][2][64][8];   //  4 KB
  __shared__ __align__(16) unsigned short Vs[2][8][64][8];   // 16 KB
  const int tid = threadIdx.x;

  if (blockIdx.z == 4) {
    if (blockIdx.y >= BB) return;
    const int h = blockIdx.x, b = blockIdx.y;
    const int d = tid >> 2, part = tid & 3;
    const unsigned short* row = Vt + ((size_t)b*DM + h*DK + d)*LL + part*512;
    float s = 0.f;
    for (int i = 0; i < 512; i += 8) {
      const s8v v = *(const s8v*)&row[i];
#pragma unroll
      for (int j = 0; j < 8; ++j) s += b2f((unsigned short)v[j]);
    }
    s += __shfl_xor(s, 1);
    s += __shfl_xor(s, 2);
    if (part == 0) Vsum[((size_t)b*NH + h)*DK + d] = s;
    return;
  }

  const int q0 = blockIdx.x * 128, h = blockIdx.y;
  const int b = blockIdx.z & (BB - 1), ksp = blockIdx.z >> 1;
  const int kbeg = ksp * (LL / NSPL);
  const int NT = (LL / NSPL) / 64;
  const int w = tid >> 6, lane = tid & 63;
  const int l31 = lane & 31, hi = lane >> 5;

  const s8v qfrag = *(const s8v*)&Qp[
      (((size_t)b*NH + h)*LL + q0 + w*32 + l31)*RK + hi*8];

  const int sr = tid >> 2, sp = tid & 3;
  const unsigned short* __restrict__ Vrow =
      Vt + ((size_t)b*DM + h*DK + sr)*LL + kbeg;
  const unsigned short* __restrict__ Kbase =
      Kp + (((size_t)b*NH + h)*LL + kbeg + sr)*RK + sp*4;
  const unsigned char*  __restrict__ Mrow = msk + (size_t)b*LL + kbeg + lane;

  u2v kpre; s8v vpre0, vpre1;
  unsigned char mcur, mnext;

  kpre  = *(const u2v*)&Kbase[0];
  vpre0 = *(const s8v*)&Vrow[sp*16];
  vpre1 = *(const s8v*)&Vrow[sp*16 + 8];
  mcur  = Mrow[0];
  *(u2v*)&Ks[0][sp>>1][sr][(sp&1)*4] = kpre;
  *(s8v*)&Vs[0][sp*2][sr][0]   = vpre0;
  *(s8v*)&Vs[0][sp*2+1][sr][0] = vpre1;
  kpre  = *(const u2v*)&Kbase[(size_t)64*RK];
  vpre0 = *(const s8v*)&Vrow[64 + sp*16];
  vpre1 = *(const s8v*)&Vrow[64 + sp*16 + 8];
  mnext = Mrow[64];
  __syncthreads();

  f16v acc0, acc1, z16;
#pragma unroll
  for (int i = 0; i < 16; ++i) { acc0[i] = 0.f; acc1[i] = 0.f; z16[i] = 0.f; }
  float den = 0.f;

  for (int t = 0; t < NT; ++t) {
    const int cur = t & 1;
    const unsigned long long mb = __ballot(mcur != 0);

    const s8v kf0 = *(const s8v*)&Ks[cur][hi][l31][0];
    const s8v kf1 = *(const s8v*)&Ks[cur][hi][32 + l31][0];

    const f16v s0 = __builtin_amdgcn_mfma_f32_32x32x16_bf16(kf0, qfrag, z16, 0, 0, 0);
    const f16v s1 = __builtin_amdgcn_mfma_f32_32x32x16_bf16(kf1, qfrag, z16, 0, 0, 0);

    unsigned int Pd[2][4][2];
    if (__builtin_expect(mb != 0ull, 0))
      softmax_pack<true >(s0, s1, mb, hi, den, Pd);
    else
      softmax_pack<false>(s0, s1, mb, hi, den, Pd);

#pragma unroll
    for (int kc = 0; kc < 4; ++kc) {
      const int nt = kc >> 1, a = (kc & 1)*2;
      const u2v r0 = __builtin_amdgcn_permlane32_swap(
          Pd[nt][a][0], Pd[nt][a+1][0], false, false);
      const u2v r1 = __builtin_amdgcn_permlane32_swap(
          Pd[nt][a][1], Pd[nt][a+1][1], false, false);
      u4v efi;
      efi[0] = r0[0];
      efi[1] = r1[0];
      efi[2] = r0[1];
      efi[3] = r1[1];
      const s8v ef = __builtin_bit_cast(s8v, efi);
      const s8v vf0 = *(const s8v*)&Vs[cur][kc*2 + hi][l31][0];
      const s8v vf1 = *(const s8v*)&Vs[cur][kc*2 + hi][32 + l31][0];
      acc0 = __builtin_amdgcn_mfma_f32_32x32x16_bf16(ef, vf0, acc0, 0, 0, 0);
      acc1 = __builtin_amdgcn_mfma_f32_32x32x16_bf16(ef, vf1, acc1, 0, 0, 0);
    }

    if (t + 1 < NT) {
      *(u2v*)&Ks[cur^1][sp>>1][sr][(sp&1)*4] = kpre;
      *(s8v*)&Vs[cur^1][sp*2][sr][0]   = vpre0;
      *(s8v*)&Vs[cur^1][sp*2+1][sr][0] = vpre1;
      const int tn = (t + 2 < NT) ? t + 2 : NT - 1;
      kpre  = *(const u2v*)&Kbase[(size_t)tn*64*RK];
      vpre0 = *(const s8v*)&Vrow[tn*64 + sp*16];
      vpre1 = *(const s8v*)&Vrow[tn*64 + sp*16 + 8];
      mcur  = mnext;
      mnext = Mrow[tn*64];
    }
    __syncthreads();
  }

  den += __shfl_xor(den, 32);
  if (hi == 0)
    denP[(((size_t)ksp*BB + b)*NH + h)*LL + q0 + w*32 + l31] = den;

#pragma unroll
  for (int rg = 0; rg < 16; ++rg) {
    const int qr = (rg & 3) + 8*(rg >> 2) + 4*hi;
    const size_t pbase =
        ((size_t)ksp*TT + b*LL + q0 + w*32 + qr)*DM + h*DK;
    P[pbase + l31]      = f2b(acc0[rg]);
    P[pbase + 32 + l31] = f2b(acc1[rg]);
  }
}

// ---------------------------------------------------------------------------
// outred: out = ctx @ Wo^T + bo, ctx never materialized.
// P0/P1 tiles DMA-staged like A; reduce math at frag-read time using LDS
// tables vsS (Vsum[b][dm]) and invS (1/(den0+den1) per [row][h]).
// 2-phase dbuf pipeline, 4 DMA/iter, one vmcnt(0)+barrier per iter.
// ---------------------------------------------------------------------------
__global__ __launch_bounds__(256) void outred_k(
    const unsigned short* __restrict__ P, const float* __restrict__ Vsum,
    const float* __restrict__ denP, const unsigned short* __restrict__ Bg,
    const float* __restrict__ bias, float* __restrict__ C) {
  __shared__ __align__(16) unsigned short P0s[2][2048];   //  8 KB
  __shared__ __align__(16) unsigned short P1s[2][2048];   //  8 KB
  __shared__ __align__(16) unsigned short Bs[2][4096];    // 16 KB
  __shared__ float vsS[1024];                             //  4 KB
  __shared__ float invS[64][16];                          //  4 KB
  const int f = blockIdx.x;
  const int t0 = (f & 63) * 64, n0 = (f >> 6) * 128;
  const int tid = threadIdx.x, wave = tid >> 6, lane = tid & 63;
  const int quad = lane >> 4, l15 = lane & 15;
  const int nh = wave * 32;
  const int ar = tid >> 2, ac = (tid & 3) * 8;
  const int trow = t0 + ar;
  const int b = t0 >> 11;

  // ---- tables ----
  for (int i = tid; i < 1024; i += 256)
    vsS[i] = Vsum[(size_t)b*DM + i];
  {
    const int r = tid >> 2, h0 = (tid & 3) * 4;
    const int lr = (t0 + r) & 2047;
#pragma unroll
    for (int j = 0; j < 4; ++j) {
      const int h = h0 + j;
      const float dn = denP[((size_t)b*NH + h)*LL + lr] +
                       denP[(((size_t)BB + b)*NH + h)*LL + lr];
      invS[r][h] = 1.f / fmaxf(dn, 1e-30f);
    }
  }

  auto STAGE = [&](int buf, int k0) {
    gld_lds16(&P[(size_t)trow*DM + k0 + ac],             &P0s[buf][wave*512]);
    gld_lds16(&P[((size_t)TT + trow)*DM + k0 + ac],      &P1s[buf][wave*512]);
    gld_lds16(&Bg[(size_t)(n0 + ar)*DM + k0 + ac],       &Bs[buf][wave*512]);
    gld_lds16(&Bg[(size_t)(n0 + 64 + ar)*DM + k0 + ac],  &Bs[buf][2048 + wave*512]);
  };
  STAGE(0, 0);
  asm volatile("s_waitcnt vmcnt(0) lgkmcnt(0)" ::: "memory");
  __builtin_amdgcn_s_barrier();

  const f4 z = {0.f, 0.f, 0.f, 0.f};
  f4 acc[4][2];
#pragma unroll
  for (int a = 0; a < 4; ++a) { acc[a][0] = z; acc[a][1] = z; }

  int cur = 0;
  for (int k0 = 0; k0 < DM; k0 += 32) {
    if (k0 + 32 < DM) STAGE(cur ^ 1, k0 + 32);
    const int hk = k0 >> 6;
    const f4 vq0 = *(const f4*)&vsS[k0 + quad*8];
    const f4 vq1 = *(const f4*)&vsS[k0 + quad*8 + 4];
    s8v af[4], bf[2];
#pragma unroll
    for (int ms = 0; ms < 4; ++ms) {
      const int r16 = ms*16 + l15;
      const float inv = invS[r16][hk];
      const s8v p0 = *(const s8v*)&P0s[cur][r16*32 + quad*8];
      const s8v p1 = *(const s8v*)&P1s[cur][r16*32 + quad*8];
      float e[8];
#pragma unroll
      for (int j = 0; j < 4; ++j) {
        e[j]     = (vq0[j] + b2f((unsigned short)p0[j])
                           + b2f((unsigned short)p1[j])) * inv;
        e[4 + j] = (vq1[j] + b2f((unsigned short)p0[4+j])
                           + b2f((unsigned short)p1[4+j])) * inv;
      }
      unsigned int d0, d1, d2, d3;
      asm("v_cvt_pk_bf16_f32 %0, %1, %2" : "=v"(d0) : "v"(e[0]), "v"(e[1]));
      asm("v_cvt_pk_bf16_f32 %0, %1, %2" : "=v"(d1) : "v"(e[2]), "v"(e[3]));
      asm("v_cvt_pk_bf16_f32 %0, %1, %2" : "=v"(d2) : "v"(e[4]), "v"(e[5]));
      asm("v_cvt_pk_bf16_f32 %0, %1, %2" : "=v"(d3) : "v"(e[6]), "v"(e[7]));
      u4v efi; efi[0] = d0; efi[1] = d1; efi[2] = d2; efi[3] = d3;
      af[ms] = __builtin_bit_cast(s8v, efi);
    }
#pragma unroll
    for (int ns = 0; ns < 2; ++ns)
      bf[ns] = *(const s8v*)&Bs[cur][(nh + ns*16 + l15)*32 + quad*8];
#pragma unroll
    for (int ms = 0; ms < 4; ++ms)
#pragma unroll
      for (int ns = 0; ns < 2; ++ns)
        acc[ms][ns] = __builtin_amdgcn_mfma_f32_16x16x32_bf16(
            af[ms], bf[ns], acc[ms][ns], 0, 0, 0);
    wait_vm0_barrier();
    cur ^= 1;
  }

#pragma unroll
  for (int ms = 0; ms < 4; ++ms) {
    const int tb = t0 + ms*16 + quad*4;
#pragma unroll
    for (int ns = 0; ns < 2; ++ns) {
      const int o = n0 + nh + ns*16 + l15;
      const float bv = bias[o];
      f4 a = acc[ms][ns];
#pragma unroll
      for (int rg = 0; rg < 4; ++rg)
        C[(size_t)(tb + rg)*DM + o] = a[rg] + bv;
    }
  }
}

// ---------------------------------------------------------------------------
extern "C" void kernel_launch(void* const* d_in, const int* in_sizes, int n_in,
                              void* d_out, int out_size, void* d_ws, size_t ws_size,
                              hipStream_t stream) {
  (void)in_sizes; (void)n_in; (void)out_size; (void)ws_size;
  const float* x_q   = (const float*)d_in[0];
  const float* x_kv  = (const float*)d_in[1];
  const float* Wq    = (const float*)d_in[2];
  const float* bq    = (const float*)d_in[3];
  const float* Wk    = (const float*)d_in[4];
  const float* bk    = (const float*)d_in[5];
  const float* Wv    = (const float*)d_in[6];
  const float* bv    = (const float*)d_in[7];
  const float* Wo    = (const float*)d_in[8];
  const float* bo    = (const float*)d_in[9];
  const float* U_bil = (const float*)d_in[10];
  const float* V_bil = (const float*)d_in[11];
  const unsigned char* pmask = (const unsigned char*)d_in[12];  // all-False
  float* out = (float*)d_out;

  // Workspace layout, ~33.6 MiB.
  // P ([2][TT][DM] bf16, 16 MB) aliases xq_b+xkv_b (dead after proj).
  char* w = (char*)d_ws;
  unsigned short* xq_b  = (unsigned short*)(w);             //  8 MB
  unsigned short* xkv_b = (unsigned short*)(w +  8388608);  //  8 MB
  unsigned short* Wv_b  = (unsigned short*)(w + 16777216);  //  2 MB
  unsigned short* Wo_b  = (unsigned short*)(w + 18874368);  //  2 MB
  unsigned short* Atq   = (unsigned short*)(w + 20971520);  //  0.5 MB
  unsigned short* Atk   = (unsigned short*)(w + 21495808);  //  0.5 MB
  float*          bpq   = (float*)(w + 22020096);           //  1 KB
  float*          bpk   = (float*)(w + 22021120);           //  1 KB
  unsigned short* Qp    = (unsigned short*)(w + 22022144);  //  2 MB
  unsigned short* Kp    = (unsigned short*)(w + 24119296);  //  2 MB
  unsigned short* Vt    = (unsigned short*)(w + 26216448);  //  8 MB
  float*          Vsum  = (float*)(w + 34605056);           //  8 KB
  float*          denP  = (float*)(w + 34613248);           //  512 KB
  unsigned short* Pbuf  = (unsigned short*)w;               //  16 MB aliased

  prep_k<<<3073, 256, 0, stream>>>(
      x_q, x_kv, Wv, Wo, xq_b, xkv_b, Wv_b, Wo_b,
      Wq, Wk, U_bil, V_bil, Atq, Atk, bq, bk, bpq, bpk);
  proj_k<<<512, 256, 0, stream>>>(
      xq_b, xkv_b, Atq, Atk, bpq, bpk, Qp, Kp, Wv_b, bv, Vt);
  attn_k<<<dim3(LL/128, NH, 5), 256, 0, stream>>>(
      Qp, Kp, Vt, pmask, Pbuf, denP, Vsum);
  outred_k<<<512, 256, 0, stream>>>(Pbuf, Vsum, denP, Wo_b, bo, out);
}

// Round 10
// 227.328 us; speedup vs baseline: 1.0091x; 1.0091x over previous
//
#include <hip/hip_runtime.h>
#include <hip/hip_bf16.h>

// Problem constants
#define DM   1024
#define NH   16
#define DK   64
#define RK   16
#define BB   2
#define LL   2048
#define TT   (BB*LL)
#define NSPL 2             // split-K factor

// r19: attn VALU-issue cut. (1) 0.25 score scale folded into Aq/bpq at prep
// (exact pow2). (2) softmax uses v_pk_add_f32 for (e-1) and den pairs; den
// rebased to sum(e-1)+32*NT (masked elems give -1, cancelled by count — one
// unified path). (3) Ks/Vs row dim 64->65 (region stride 1040B, !=0 mod 128)
// kills the 8-way staging bank conflicts. __launch_bounds__(256,4) pins
// VGPR<=128. proj/outred/prep otherwise identical to r18.

typedef float f4   __attribute__((ext_vector_type(4)));
typedef float f2   __attribute__((ext_vector_type(2)));
typedef float f16v __attribute__((ext_vector_type(16)));
typedef short s8v  __attribute__((ext_vector_type(8)));
typedef unsigned int u2v __attribute__((ext_vector_type(2)));
typedef unsigned int u4v __attribute__((ext_vector_type(4)));

static __device__ __forceinline__ unsigned short f2b(float f) {
  __hip_bfloat16 h = __float2bfloat16(f);
  unsigned short u;
  __builtin_memcpy(&u, &h, 2);
  return u;
}
static __device__ __forceinline__ float b2f(unsigned short u) {
  __hip_bfloat16 h;
  __builtin_memcpy(&h, &u, 2);
  return __bfloat162float(h);
}

// async global->LDS, 16 B per lane. LDS dest wave-uniform base + lane*16.
static __device__ __forceinline__ void gld_lds16(const void* g, void* l) {
  __builtin_amdgcn_global_load_lds(
      (const __attribute__((address_space(1))) unsigned int*)g,
      (__attribute__((address_space(3))) unsigned int*)l, 16, 0, 0);
}

static __device__ __forceinline__ void wait_vm0_barrier() {
  asm volatile("s_waitcnt vmcnt(0)" ::: "memory");
  __builtin_amdgcn_s_barrier();
}

// ---------------------------------------------------------------------------
// prep: blockIdx.x ranges
//   [0,1024)    cast x_q   [1024,2048) cast x_kv
//   [2048,2304) cast Wv    [2304,2560) cast Wo
//   [2560,3072) fuse_w     [3072] bias2
// Aq / bpq are pre-scaled by 0.25 (exact pow2) so attn needs no score mul.
// ---------------------------------------------------------------------------
static __device__ __forceinline__ void cast_rng(
    const float* __restrict__ s, unsigned short* __restrict__ d,
    int n4, int lb, int nb, int tid) {
  for (int i = lb*256 + tid; i < n4; i += nb*256) {
    const float4 v = ((const float4*)s)[i];
    ushort4 o;
    o.x = f2b(v.x); o.y = f2b(v.y); o.z = f2b(v.z); o.w = f2b(v.w);
    ((ushort4*)d)[i] = o;
  }
}

__global__ __launch_bounds__(256) void prep_k(
    const float* __restrict__ xq,  const float* __restrict__ xkv,
    const float* __restrict__ Wv,  const float* __restrict__ Wo,
    unsigned short* __restrict__ xq_b,  unsigned short* __restrict__ xkv_b,
    unsigned short* __restrict__ Wv_b,  unsigned short* __restrict__ Wo_b,
    const float* __restrict__ Wq,  const float* __restrict__ Wk,
    const float* __restrict__ Uq,  const float* __restrict__ Uk,
    unsigned short* __restrict__ Aq, unsigned short* __restrict__ Ak,
    const float* __restrict__ bq,  const float* __restrict__ bk,
    float* __restrict__ bpq, float* __restrict__ bpk) {
  __shared__ float sh[64*16 + 4*64];
  const int x = blockIdx.x, tid = threadIdx.x;
  if (x < 1024) {
    cast_rng(xq,  xq_b,  TT*DM/4, x,        1024, tid);
  } else if (x < 2048) {
    cast_rng(xkv, xkv_b, TT*DM/4, x - 1024, 1024, tid);
  } else if (x < 2304) {
    cast_rng(Wv,  Wv_b,  DM*DM/4, x - 2048, 256, tid);
  } else if (x < 2560) {
    cast_rng(Wo,  Wo_b,  DM*DM/4, x - 2304, 256, tid);
  } else if (x < 3072) {
    const int fidx = x - 2560;
    const int sel = fidx >> 8, f = fidx & 255;
    const float* W = sel ? Wk : Wq;
    const float* U = sel ? Uk : Uq;
    unsigned short* At = sel ? Ak : Aq;
    const float qs = sel ? 1.f : 0.25f;   // fold score scale into q side
    const int i0 = (f & 15) * 64, h = f >> 4;
    float* Us = sh;            // [64][16]
    float* Ws = sh + 1024;     // [4][64]
    const int il = tid & 63, rr = tid >> 6;
    for (int t = tid; t < 64*16; t += 256)
      Us[t] = U[(size_t)(h*DK + (t >> 4))*RK + (t & 15)];
    float acc[4] = {};
    for (int d0 = 0; d0 < DK; d0 += 4) {
      __syncthreads();
      Ws[rr*64 + il] = W[(size_t)(h*DK + d0 + rr)*DM + i0 + il];
      __syncthreads();
#pragma unroll
      for (int dd = 0; dd < 4; ++dd) {
        const float w = Ws[dd*64 + il];
#pragma unroll
        for (int j = 0; j < 4; ++j)
          acc[j] += w * Us[(d0 + dd)*16 + rr*4 + j];
      }
    }
#pragma unroll
    for (int j = 0; j < 4; ++j)
      At[(size_t)(h*RK + rr*4 + j)*DM + i0 + il] = f2b(acc[j] * qs);
  } else {
    const int h = tid >> 4, r = tid & 15;
    float aq = 0.f, ak = 0.f;
    for (int d = 0; d < DK; ++d) {
      aq += bq[h*DK + d] * Uq[(size_t)(h*DK + d)*RK + r];
      ak += bk[h*DK + d] * Uk[(size_t)(h*DK + d)*RK + r];
    }
    bpq[tid] = aq * 0.25f; bpk[tid] = ak;
  }
}

// ---------------------------------------------------------------------------
// proj: f<256 -> QpKp 64x128 GEMM; f>=256 -> Vt 128x128 GEMM.
// 2-phase dbuf pipeline (stage t+1 first, vmcnt(0)+barrier AFTER MFMA).
// ---------------------------------------------------------------------------
__global__ __launch_bounds__(256) void proj_k(
    const unsigned short* __restrict__ xq_b, const unsigned short* __restrict__ xkv_b,
    const unsigned short* __restrict__ Atq,  const unsigned short* __restrict__ Atk,
    const float* __restrict__ bpq, const float* __restrict__ bpk,
    unsigned short* __restrict__ Qp, unsigned short* __restrict__ Kp,
    const unsigned short* __restrict__ Wv_b, const float* __restrict__ bv,
    unsigned short* __restrict__ Vt) {
  __shared__ __align__(16) unsigned short shm[16384];   // 32 KB
  const int f = blockIdx.x, tid = threadIdx.x;
  const int wave = tid >> 6, lane = tid & 63;
  const int quad = lane >> 4, l15 = lane & 15;
  const int ar = tid >> 2, ac = (tid & 3) * 8;
  const f4 z = {0.f, 0.f, 0.f, 0.f};

  if (f < 256) {
    // ---- QpKp: 64x128 tile, N=256 ----
    const int xb = f & 63, yb = (f >> 6) & 1, zb = f >> 7;
    const unsigned short* Ag = zb ? xkv_b : xq_b;
    const unsigned short* Bg = zb ? Atk : Atq;
    const float* bias = zb ? bpk : bpq;
    unsigned short* C = zb ? Kp : Qp;
    unsigned short* Xs = shm;          // [2][2048]
    unsigned short* Bq = shm + 4096;   // [2][4096]
    const int t0 = xb*64, n0 = yb*128, nh = wave*32;
    f4 acc[4][2];
#pragma unroll
    for (int a = 0; a < 4; ++a) { acc[a][0] = z; acc[a][1] = z; }

    auto STAGE = [&](int buf, int k0) {
      gld_lds16(&Ag[(size_t)(t0 + ar)*DM + k0 + ac],      &Xs[buf*2048 + wave*512]);
      gld_lds16(&Bg[(size_t)(n0 + ar)*DM + k0 + ac],      &Bq[buf*4096 + wave*512]);
      gld_lds16(&Bg[(size_t)(n0 + 64 + ar)*DM + k0 + ac], &Bq[buf*4096 + 2048 + wave*512]);
    };
    STAGE(0, 0);
    wait_vm0_barrier();
    int cur = 0;
    for (int k0 = 0; k0 < DM; k0 += 32) {
      if (k0 + 32 < DM) STAGE(cur ^ 1, k0 + 32);
      s8v af[4], bf[2];
#pragma unroll
      for (int ms = 0; ms < 4; ++ms)
        af[ms] = *(const s8v*)&Xs[cur*2048 + (ms*16 + l15)*32 + quad*8];
#pragma unroll
      for (int ns = 0; ns < 2; ++ns)
        bf[ns] = *(const s8v*)&Bq[cur*4096 + (nh + ns*16 + l15)*32 + quad*8];
#pragma unroll
      for (int ms = 0; ms < 4; ++ms)
#pragma unroll
        for (int ns = 0; ns < 2; ++ns)
          acc[ms][ns] = __builtin_amdgcn_mfma_f32_16x16x32_bf16(
              af[ms], bf[ns], acc[ms][ns], 0, 0, 0);
      wait_vm0_barrier();
      cur ^= 1;
    }
#pragma unroll
    for (int ms = 0; ms < 4; ++ms) {
      const int tb = t0 + ms*16 + quad*4;
#pragma unroll
      for (int ns = 0; ns < 2; ++ns) {
        const int o = n0 + nh + ns*16 + l15;
        const float bvv = bias[o];
        f4 a = acc[ms][ns];
#pragma unroll
        for (int rg = 0; rg < 4; ++rg) {
          const int tt = tb + rg;   // packed [b][h][l][16]
          C[(((size_t)(tt >> 11)*NH + (o >> 4))*LL + (tt & 2047))*RK + (o & 15)]
              = f2b(a[rg] + bvv);
        }
      }
    }
  } else {
    // ---- Vt: 128x128 tile ----
    const int g = f - 256, gx = g & 31, gy = g >> 5;
    unsigned short* As = shm;          // [2][4096]
    unsigned short* Bs = shm + 8192;   // [2][4096]
    const int t0 = gx*128, n0 = gy*128;
    f4 acc[2][8];
#pragma unroll
    for (int m = 0; m < 2; ++m)
#pragma unroll
      for (int n = 0; n < 8; ++n) acc[m][n] = z;

    auto STAGE = [&](int buf, int k0) {
      gld_lds16(&xkv_b[(size_t)(t0 + ar)*DM + k0 + ac],      &As[buf*4096 + wave*512]);
      gld_lds16(&xkv_b[(size_t)(t0 + 64 + ar)*DM + k0 + ac], &As[buf*4096 + 2048 + wave*512]);
      gld_lds16(&Wv_b[(size_t)(n0 + ar)*DM + k0 + ac],       &Bs[buf*4096 + wave*512]);
      gld_lds16(&Wv_b[(size_t)(n0 + 64 + ar)*DM + k0 + ac],  &Bs[buf*4096 + 2048 + wave*512]);
    };
    STAGE(0, 0);
    wait_vm0_barrier();
    int cur = 0;
    for (int k0 = 0; k0 < DM; k0 += 32) {
      if (k0 + 32 < DM) STAGE(cur ^ 1, k0 + 32);
      s8v af[2], bf[8];
#pragma unroll
      for (int ms = 0; ms < 2; ++ms)
        af[ms] = *(const s8v*)&As[cur*4096 + (wave*32 + ms*16 + l15)*32 + quad*8];
#pragma unroll
      for (int ns = 0; ns < 8; ++ns)
        bf[ns] = *(const s8v*)&Bs[cur*4096 + (ns*16 + l15)*32 + quad*8];
#pragma unroll
      for (int ms = 0; ms < 2; ++ms)
#pragma unroll
        for (int ns = 0; ns < 8; ++ns)
          acc[ms][ns] = __builtin_amdgcn_mfma_f32_16x16x32_bf16(
              af[ms], bf[ns], acc[ms][ns], 0, 0, 0);
      wait_vm0_barrier();
      cur ^= 1;
    }
#pragma unroll
    for (int ms = 0; ms < 2; ++ms) {
      const int tb = t0 + wave*32 + ms*16 + quad*4;
#pragma unroll
      for (int ns = 0; ns < 8; ++ns) {
        const int o = n0 + ns*16 + l15;
        const float bvv = bv[o];
        f4 a = acc[ms][ns];
        const int bb = tb >> 11, l = tb & 2047;   // Vt[b][o][l]
        ushort4 pk;
        pk.x = f2b(a[0] + bvv); pk.y = f2b(a[1] + bvv);
        pk.z = f2b(a[2] + bvv); pk.w = f2b(a[3] + bvv);
        *(ushort4*)&Vt[((size_t)bb*DM + o)*LL + l] = pk;
      }
    }
  }
}

// ---------------------------------------------------------------------------
// softmax + bf16-pack, VALU-lean: scores arrive PRE-SCALED (0.25 folded into
// Qp). E' = e-1 via v_pk_add_f32; den accumulated as sum(E') pairs (count
// added at the end: masked elems give e=0 -> E'=-1, cancelled by +1 of count,
// so one unified formula for both paths).
// ---------------------------------------------------------------------------
template<bool MASKED>
static __device__ __forceinline__ void softmax_pack(
    const f16v& s0, const f16v& s1, const unsigned long long mb, const int hi,
    f2& den2, unsigned int (&Pd)[2][4][2]) {
  const f2 neg1 = {-1.f, -1.f};
#pragma unroll
  for (int nt = 0; nt < 2; ++nt) {
    const f16v& sv = nt ? s1 : s0;
#pragma unroll
    for (int r = 0; r < 4; ++r) {
#pragma unroll
      for (int jp = 0; jp < 2; ++jp) {
        f2 em2;
        em2[0] = __expf(sv[r*4 + jp*2]);
        em2[1] = __expf(sv[r*4 + jp*2 + 1]);
        if (MASKED) {
          const int kl = nt*32 + jp*2 + 8*r + 4*hi;
          if ((mb >> kl) & 1ull)       em2[0] = 0.f;
          if ((mb >> (kl + 1)) & 1ull) em2[1] = 0.f;
        }
        f2 ep2;
        asm("v_pk_add_f32 %0, %1, %2" : "=v"(ep2) : "v"(em2), "v"(neg1));
        asm("v_pk_add_f32 %0, %0, %1" : "+v"(den2) : "v"(ep2));
        asm("v_cvt_pk_bf16_f32 %0, %1, %2"
            : "=v"(Pd[nt][r][jp]) : "v"(ep2[0]), "v"(ep2[1]));
      }
    }
  }
}

// ---------------------------------------------------------------------------
// attn: z<4 -> attention (split-K + permlane32_swap); z==4, y<BB -> vsum.
// P layout: [split][t][dm] bf16. Ks/Vs rows padded 64->65 (region stride
// 1040 B != 0 mod 128 -> staging bank conflicts spread).
// ---------------------------------------------------------------------------
__global__ __launch_bounds__(256, 4) void attn_k(
    const unsigned short* __restrict__ Qp, const unsigned short* __restrict__ Kp,
    const unsigned short* __restrict__ Vt,
    const unsigned char* __restrict__ msk,
    unsigned short* __restrict__ P, float* __restrict__ denP,
    float* __restrict__ Vsum) {
  __shared__ __align__(16) unsigned short Ks[2][2][65][8];   // ~4.1 KB
  __shared__ __align__(16) unsigned short Vs[2][8][65][8];   // ~16.3 KB
  const int tid = threadIdx.x;

  if (blockIdx.z == 4) {
    if (blockIdx.y >= BB) return;
    const int h = blockIdx.x, b = blockIdx.y;
    const int d = tid >> 2, part = tid & 3;
    const unsigned short* row = Vt + ((size_t)b*DM + h*DK + d)*LL + part*512;
    float s = 0.f;
    for (int i = 0; i < 512; i += 8) {
      const s8v v = *(const s8v*)&row[i];
#pragma unroll
      for (int j = 0; j < 8; ++j) s += b2f((unsigned short)v[j]);
    }
    s += __shfl_xor(s, 1);
    s += __shfl_xor(s, 2);
    if (part == 0) Vsum[((size_t)b*NH + h)*DK + d] = s;
    return;
  }

  const int q0 = blockIdx.x * 128, h = blockIdx.y;
  const int b = blockIdx.z & (BB - 1), ksp = blockIdx.z >> 1;
  const int kbeg = ksp * (LL / NSPL);
  const int NT = (LL / NSPL) / 64;                           // 16 tiles
  const int w = tid >> 6, lane = tid & 63;
  const int l31 = lane & 31, hi = lane >> 5;

  const s8v qfrag = *(const s8v*)&Qp[
      (((size_t)b*NH + h)*LL + q0 + w*32 + l31)*RK + hi*8];

  const int sr = tid >> 2, sp = tid & 3;
  const unsigned short* __restrict__ Vrow =
      Vt + ((size_t)b*DM + h*DK + sr)*LL + kbeg;
  const unsigned short* __restrict__ Kbase =
      Kp + (((size_t)b*NH + h)*LL + kbeg + sr)*RK + sp*4;
  const unsigned char*  __restrict__ Mrow = msk + (size_t)b*LL + kbeg + lane;

  u2v kpre; s8v vpre0, vpre1;
  unsigned char mcur, mnext;

  kpre  = *(const u2v*)&Kbase[0];
  vpre0 = *(const s8v*)&Vrow[sp*16];
  vpre1 = *(const s8v*)&Vrow[sp*16 + 8];
  mcur  = Mrow[0];
  *(u2v*)&Ks[0][sp>>1][sr][(sp&1)*4] = kpre;
  *(s8v*)&Vs[0][sp*2][sr][0]   = vpre0;
  *(s8v*)&Vs[0][sp*2+1][sr][0] = vpre1;
  kpre  = *(const u2v*)&Kbase[(size_t)64*RK];
  vpre0 = *(const s8v*)&Vrow[64 + sp*16];
  vpre1 = *(const s8v*)&Vrow[64 + sp*16 + 8];
  mnext = Mrow[64];
  __syncthreads();

  f16v acc0, acc1, z16;
#pragma unroll
  for (int i = 0; i < 16; ++i) { acc0[i] = 0.f; acc1[i] = 0.f; z16[i] = 0.f; }
  f2 den2 = {0.f, 0.f};

  for (int t = 0; t < NT; ++t) {
    const int cur = t & 1;
    const unsigned long long mb = __ballot(mcur != 0);

    const s8v kf0 = *(const s8v*)&Ks[cur][hi][l31][0];
    const s8v kf1 = *(const s8v*)&Ks[cur][hi][32 + l31][0];

    const f16v s0 = __builtin_amdgcn_mfma_f32_32x32x16_bf16(kf0, qfrag, z16, 0, 0, 0);
    const f16v s1 = __builtin_amdgcn_mfma_f32_32x32x16_bf16(kf1, qfrag, z16, 0, 0, 0);

    unsigned int Pd[2][4][2];
    if (__builtin_expect(mb != 0ull, 0))
      softmax_pack<true >(s0, s1, mb, hi, den2, Pd);
    else
      softmax_pack<false>(s0, s1, mb, hi, den2, Pd);

#pragma unroll
    for (int kc = 0; kc < 4; ++kc) {
      const int nt = kc >> 1, a = (kc & 1)*2;
      const u2v r0 = __builtin_amdgcn_permlane32_swap(
          Pd[nt][a][0], Pd[nt][a+1][0], false, false);
      const u2v r1 = __builtin_amdgcn_permlane32_swap(
          Pd[nt][a][1], Pd[nt][a+1][1], false, false);
      u4v efi;
      efi[0] = r0[0];
      efi[1] = r1[0];
      efi[2] = r0[1];
      efi[3] = r1[1];
      const s8v ef = __builtin_bit_cast(s8v, efi);
      const s8v vf0 = *(const s8v*)&Vs[cur][kc*2 + hi][l31][0];
      const s8v vf1 = *(const s8v*)&Vs[cur][kc*2 + hi][32 + l31][0];
      acc0 = __builtin_amdgcn_mfma_f32_32x32x16_bf16(ef, vf0, acc0, 0, 0, 0);
      acc1 = __builtin_amdgcn_mfma_f32_32x32x16_bf16(ef, vf1, acc1, 0, 0, 0);
    }

    if (t + 1 < NT) {
      *(u2v*)&Ks[cur^1][sp>>1][sr][(sp&1)*4] = kpre;
      *(s8v*)&Vs[cur^1][sp*2][sr][0]   = vpre0;
      *(s8v*)&Vs[cur^1][sp*2+1][sr][0] = vpre1;
      const int tn = (t + 2 < NT) ? t + 2 : NT - 1;
      kpre  = *(const u2v*)&Kbase[(size_t)tn*64*RK];
      vpre0 = *(const s8v*)&Vrow[tn*64 + sp*16];
      vpre1 = *(const s8v*)&Vrow[tn*64 + sp*16 + 8];
      mcur  = mnext;
      mnext = Mrow[tn*64];
    }
    __syncthreads();
  }

  // den = sum(E') + count (count = 32 elems/tile * NT tiles, exact)
  float den = den2[0] + den2[1] + (float)(32 * NT);
  den += __shfl_xor(den, 32);
  if (hi == 0)
    denP[(((size_t)ksp*BB + b)*NH + h)*LL + q0 + w*32 + l31] = den;

#pragma unroll
  for (int rg = 0; rg < 16; ++rg) {
    const int qr = (rg & 3) + 8*(rg >> 2) + 4*hi;
    const size_t pbase =
        ((size_t)ksp*TT + b*LL + q0 + w*32 + qr)*DM + h*DK;
    P[pbase + l31]      = f2b(acc0[rg]);
    P[pbase + 32 + l31] = f2b(acc1[rg]);
  }
}

// ---------------------------------------------------------------------------
// outred: out = ctx @ Wo^T + bo, ctx never materialized.
// P0/P1 tiles DMA-staged like A; reduce math at frag-read time using LDS
// tables vsS (Vsum[b][dm]) and invS (1/(den0+den1) per [row][h]).
// 2-phase dbuf pipeline, 4 DMA/iter, one vmcnt(0)+barrier per iter.
// ---------------------------------------------------------------------------
__global__ __launch_bounds__(256) void outred_k(
    const unsigned short* __restrict__ P, const float* __restrict__ Vsum,
    const float* __restrict__ denP, const unsigned short* __restrict__ Bg,
    const float* __restrict__ bias, float* __restrict__ C) {
  __shared__ __align__(16) unsigned short P0s[2][2048];   //  8 KB
  __shared__ __align__(16) unsigned short P1s[2][2048];   //  8 KB
  __shared__ __align__(16) unsigned short Bs[2][4096];    // 16 KB
  __shared__ float vsS[1024];                             //  4 KB
  __shared__ float invS[64][16];                          //  4 KB
  const int f = blockIdx.x;
  const int t0 = (f & 63) * 64, n0 = (f >> 6) * 128;
  const int tid = threadIdx.x, wave = tid >> 6, lane = tid & 63;
  const int quad = lane >> 4, l15 = lane & 15;
  const int nh = wave * 32;
  const int ar = tid >> 2, ac = (tid & 3) * 8;
  const int trow = t0 + ar;
  const int b = t0 >> 11;

  // ---- tables ----
  for (int i = tid; i < 1024; i += 256)
    vsS[i] = Vsum[(size_t)b*DM + i];
  {
    const int r = tid >> 2, h0 = (tid & 3) * 4;
    const int lr = (t0 + r) & 2047;
#pragma unroll
    for (int j = 0; j < 4; ++j) {
      const int h = h0 + j;
      const float dn = denP[((size_t)b*NH + h)*LL + lr] +
                       denP[(((size_t)BB + b)*NH + h)*LL + lr];
      invS[r][h] = 1.f / fmaxf(dn, 1e-30f);
    }
  }

  auto STAGE = [&](int buf, int k0) {
    gld_lds16(&P[(size_t)trow*DM + k0 + ac],             &P0s[buf][wave*512]);
    gld_lds16(&P[((size_t)TT + trow)*DM + k0 + ac],      &P1s[buf][wave*512]);
    gld_lds16(&Bg[(size_t)(n0 + ar)*DM + k0 + ac],       &Bs[buf][wave*512]);
    gld_lds16(&Bg[(size_t)(n0 + 64 + ar)*DM + k0 + ac],  &Bs[buf][2048 + wave*512]);
  };
  STAGE(0, 0);
  asm volatile("s_waitcnt vmcnt(0) lgkmcnt(0)" ::: "memory");
  __builtin_amdgcn_s_barrier();

  const f4 z = {0.f, 0.f, 0.f, 0.f};
  f4 acc[4][2];
#pragma unroll
  for (int a = 0; a < 4; ++a) { acc[a][0] = z; acc[a][1] = z; }

  int cur = 0;
  for (int k0 = 0; k0 < DM; k0 += 32) {
    if (k0 + 32 < DM) STAGE(cur ^ 1, k0 + 32);
    const int hk = k0 >> 6;
    const f4 vq0 = *(const f4*)&vsS[k0 + quad*8];
    const f4 vq1 = *(const f4*)&vsS[k0 + quad*8 + 4];
    s8v af[4], bf[2];
#pragma unroll
    for (int ms = 0; ms < 4; ++ms) {
      const int r16 = ms*16 + l15;
      const float inv = invS[r16][hk];
      const s8v p0 = *(const s8v*)&P0s[cur][r16*32 + quad*8];
      const s8v p1 = *(const s8v*)&P1s[cur][r16*32 + quad*8];
      float e[8];
#pragma unroll
      for (int j = 0; j < 4; ++j) {
        e[j]     = (vq0[j] + b2f((unsigned short)p0[j])
                           + b2f((unsigned short)p1[j])) * inv;
        e[4 + j] = (vq1[j] + b2f((unsigned short)p0[4+j])
                           + b2f((unsigned short)p1[4+j])) * inv;
      }
      unsigned int d0, d1, d2, d3;
      asm("v_cvt_pk_bf16_f32 %0, %1, %2" : "=v"(d0) : "v"(e[0]), "v"(e[1]));
      asm("v_cvt_pk_bf16_f32 %0, %1, %2" : "=v"(d1) : "v"(e[2]), "v"(e[3]));
      asm("v_cvt_pk_bf16_f32 %0, %1, %2" : "=v"(d2) : "v"(e[4]), "v"(e[5]));
      asm("v_cvt_pk_bf16_f32 %0, %1, %2" : "=v"(d3) : "v"(e[6]), "v"(e[7]));
      u4v efi; efi[0] = d0; efi[1] = d1; efi[2] = d2; efi[3] = d3;
      af[ms] = __builtin_bit_cast(s8v, efi);
    }
#pragma unroll
    for (int ns = 0; ns < 2; ++ns)
      bf[ns] = *(const s8v*)&Bs[cur][(nh + ns*16 + l15)*32 + quad*8];
#pragma unroll
    for (int ms = 0; ms < 4; ++ms)
#pragma unroll
      for (int ns = 0; ns < 2; ++ns)
        acc[ms][ns] = __builtin_amdgcn_mfma_f32_16x16x32_bf16(
            af[ms], bf[ns], acc[ms][ns], 0, 0, 0);
    wait_vm0_barrier();
    cur ^= 1;
  }

#pragma unroll
  for (int ms = 0; ms < 4; ++ms) {
    const int tb = t0 + ms*16 + quad*4;
#pragma unroll
    for (int ns = 0; ns < 2; ++ns) {
      const int o = n0 + nh + ns*16 + l15;
      const float bv = bias[o];
      f4 a = acc[ms][ns];
#pragma unroll
      for (int rg = 0; rg < 4; ++rg)
        C[(size_t)(tb + rg)*DM + o] = a[rg] + bv;
    }
  }
}

// ---------------------------------------------------------------------------
extern "C" void kernel_launch(void* const* d_in, const int* in_sizes, int n_in,
                              void* d_out, int out_size, void* d_ws, size_t ws_size,
                              hipStream_t stream) {
  (void)in_sizes; (void)n_in; (void)out_size; (void)ws_size;
  const float* x_q   = (const float*)d_in[0];
  const float* x_kv  = (const float*)d_in[1];
  const float* Wq    = (const float*)d_in[2];
  const float* bq    = (const float*)d_in[3];
  const float* Wk    = (const float*)d_in[4];
  const float* bk    = (const float*)d_in[5];
  const float* Wv    = (const float*)d_in[6];
  const float* bv    = (const float*)d_in[7];
  const float* Wo    = (const float*)d_in[8];
  const float* bo    = (const float*)d_in[9];
  const float* U_bil = (const float*)d_in[10];
  const float* V_bil = (const float*)d_in[11];
  const unsigned char* pmask = (const unsigned char*)d_in[12];  // all-False
  float* out = (float*)d_out;

  // Workspace layout, ~33.6 MiB.
  // P ([2][TT][DM] bf16, 16 MB) aliases xq_b+xkv_b (dead after proj).
  char* w = (char*)d_ws;
  unsigned short* xq_b  = (unsigned short*)(w);             //  8 MB
  unsigned short* xkv_b = (unsigned short*)(w +  8388608);  //  8 MB
  unsigned short* Wv_b  = (unsigned short*)(w + 16777216);  //  2 MB
  unsigned short* Wo_b  = (unsigned short*)(w + 18874368);  //  2 MB
  unsigned short* Atq   = (unsigned short*)(w + 20971520);  //  0.5 MB
  unsigned short* Atk   = (unsigned short*)(w + 21495808);  //  0.5 MB
  float*          bpq   = (float*)(w + 22020096);           //  1 KB
  float*          bpk   = (float*)(w + 22021120);           //  1 KB
  unsigned short* Qp    = (unsigned short*)(w + 22022144);  //  2 MB
  unsigned short* Kp    = (unsigned short*)(w + 24119296);  //  2 MB
  unsigned short* Vt    = (unsigned short*)(w + 26216448);  //  8 MB
  float*          Vsum  = (float*)(w + 34605056);           //  8 KB
  float*          denP  = (float*)(w + 34613248);           //  512 KB
  unsigned short* Pbuf  = (unsigned short*)w;               //  16 MB aliased

  prep_k<<<3073, 256, 0, stream>>>(
      x_q, x_kv, Wv, Wo, xq_b, xkv_b, Wv_b, Wo_b,
      Wq, Wk, U_bil, V_bil, Atq, Atk, bq, bk, bpq, bpk);
  proj_k<<<512, 256, 0, stream>>>(
      xq_b, xkv_b, Atq, Atk, bpq, bpk, Qp, Kp, Wv_b, bv, Vt);
  attn_k<<<dim3(LL/128, NH, 5), 256, 0, stream>>>(
      Qp, Kp, Vt, pmask, Pbuf, denP, Vsum);
  outred_k<<<512, 256, 0, stream>>>(Pbuf, Vsum, denP, Wo_b, bo, out);
}